// Round 12
// baseline (107.183 us; speedup 1.0000x reference)
//
#include <hip/hip_runtime.h>
#include <hip/hip_fp16.h>
#include <math.h>

#define N_NODES 50000
#define N_EDGES 800000
#define NBUCK 196             // ceil(N/256) coarse buckets (rows r>>8)
#define BROWS 256             // rows per bucket
#define GRID_P 256            // partition blocks in D1
#define SLICE_CAP 48          // per (bucket,block) slice cap; Poisson(16)
#define EMAX 5120             // per-bucket staged edges (unpadded)
#define EMAXP 6400            // per-bucket padded capacity
#define SENT 50000            // sentinel col: a[SENT]=0, yh row zeroed
#define SENTPAIR 0xC350C350u  // (SENT<<16)|SENT

typedef _Float16 h4 __attribute__((ext_vector_type(4)));
typedef float f32x4 __attribute__((ext_vector_type(4)));

// ---------------------------------------------------------------------------
// D1: partition ∥ proj, one dispatch, NO intra-dispatch dependencies.
// Blocks 0..255: bucket-partition edges (R11 LDS-staged slices + coalesced
// flush). Blocks 256..451: proj — each block computes avec AND Wc itself
// (1M FMAs ≈ 1µs, removes the K1->proj dependency), then 4 MFMA tiles with
// x direct global->fragment, writing yh and a[r]=exp(x.avec) (R9-validated
// numerics: identical absmax). Proj rides the second CU slot under the
// partition wall -> D1 wall ≈ partition alone.
// ---------------------------------------------------------------------------
union ShD1 {
  struct {
    int cur[NBUCK];
    unsigned sl[NBUCK * SLICE_CAP];  // 37.6KB block-private slices
  } q;
  struct {
    __half Wcs[64 * 132];  // [col][k], stride 132 halves
    float avs[128];
  } p;
};

__global__ __launch_bounds__(1024, 8) void part_proj(
    const int* __restrict__ ei, const float* __restrict__ x,
    const float* __restrict__ Wl, const float* __restrict__ att,
    const float* __restrict__ Wo, float* __restrict__ Zp,
    float* __restrict__ a, __half2* __restrict__ yh,
    unsigned* __restrict__ part, unsigned* __restrict__ cntm) {
  __shared__ ShD1 sh;
  const int bid = blockIdx.x;
  const int tid = threadIdx.x;

  if (bid < GRID_P) {
    // ================= partition role (R11, unchanged) =================
    for (int i = tid; i < NBUCK; i += 1024) sh.q.cur[i] = 0;
    __syncthreads();
    const int G = GRID_P * 1024;
    for (int e = bid * 1024 + tid; e < N_EDGES; e += 2 * G) {
      const int e1 = e + G;
      const bool v1 = e1 < N_EDGES;
      const int r0 = ei[e];
      const int c0 = ei[N_EDGES + e];
      int r1 = 0, c1 = 0;
      if (v1) {
        r1 = ei[e1];
        c1 = ei[N_EDGES + e1];
      }
      const int b0 = r0 >> 8;
      const int p0 = atomicAdd(&sh.q.cur[b0], 1);
      if (p0 < SLICE_CAP)
        sh.q.sl[b0 * SLICE_CAP + p0] =
            ((unsigned)(r0 & 255) << 16) | (unsigned)c0;
      if (v1) {
        const int b1 = r1 >> 8;
        const int p1 = atomicAdd(&sh.q.cur[b1], 1);
        if (p1 < SLICE_CAP)
          sh.q.sl[b1 * SLICE_CAP + p1] =
              ((unsigned)(r1 & 255) << 16) | (unsigned)c1;
      }
    }
    __syncthreads();
    const int lane = tid & 63;
    const int wv = tid >> 6;
    for (int b2 = wv; b2 < NBUCK; b2 += 16) {
      const int n = min(sh.q.cur[b2], SLICE_CAP);
      if (lane < n)
        part[((size_t)b2 * GRID_P + bid) * SLICE_CAP + lane] =
            sh.q.sl[b2 * SLICE_CAP + lane];
    }
    for (int i = tid; i < NBUCK; i += 1024)
      cntm[i * GRID_P + bid] = (unsigned)min(sh.q.cur[i], SLICE_CAP);
    return;
  }

  // ================= proj role: self-contained (own avec + Wc) ==========
  const int pb = bid - GRID_P;  // 0..195
  // avec = 0.5 * Wl @ att (same chain as before -> identical bits)
  if (tid < 128) {
    float acc = 0.f;
    for (int m = 0; m < 128; ++m)
      acc = fmaf(Wl[tid * 128 + m], att[m], acc);
    sh.p.avs[tid] = 0.5f * acc;
  }
  // Wc = Wl @ Wo, fp16 into LDS directly (8 elems/thread; same fmaf chain
  // then __float2half -> bit-identical to the old global-Wc path)
  for (int e8 = 0; e8 < 8; ++e8) {
    const int idx = e8 * 1024 + tid;   // 8192 = 128 x 64
    const int i = idx >> 6, j = idx & 63;
    float acc = 0.f;
    for (int m = 0; m < 128; ++m)
      acc = fmaf(Wl[i * 128 + m], Wo[m * 64 + j], acc);
    sh.p.Wcs[j * 132 + i] = __float2half(acc);
  }
  if (pb == 0) {  // sentinels + Zp=0 (consumed from D2 onward)
    if (tid == 1023) a[SENT] = 0.f;
    if (tid == 959) Zp[0] = 0.f;
    if (tid >= 960 && tid < 992)
      yh[(size_t)SENT * 32 + (tid - 960)] = __floats2half2_rn(0.f, 0.f);
  }
  __syncthreads();

  const int g4 = tid >> 8;       // tile-in-block 0..3
  const int t = pb * 4 + g4;     // global tile id (<= 783)
  const int row0 = t * 64;
  if (row0 >= N_NODES) return;   // after the only barrier: safe
  const int w = (tid >> 6) & 3;  // wave-in-tile
  const int l = tid & 63;
  const int lr = l & 15;
  const int lg = l >> 4;
  const int r = row0 + w * 16 + lr;  // this lane's x row
  const bool valid = r < N_NODES;
  const float* xrow = x + (size_t)(valid ? r : 0) * 128;

  f32x4 acc[4];
#pragma unroll
  for (int ct = 0; ct < 4; ++ct) acc[ct] = (f32x4){0.f, 0.f, 0.f, 0.f};
  float pdot = 0.f;

#pragma unroll
  for (int ks = 0; ks < 8; ++ks) {
    float4 xv = *(const float4*)(xrow + ks * 16 + lg * 4);
    if (!valid) xv = make_float4(0.f, 0.f, 0.f, 0.f);
    pdot += xv.x * sh.p.avs[ks * 16 + lg * 4] +
            xv.y * sh.p.avs[ks * 16 + lg * 4 + 1] +
            xv.z * sh.p.avs[ks * 16 + lg * 4 + 2] +
            xv.w * sh.p.avs[ks * 16 + lg * 4 + 3];
    h4 xb;
    xb[0] = (_Float16)xv.x;
    xb[1] = (_Float16)xv.y;
    xb[2] = (_Float16)xv.z;
    xb[3] = (_Float16)xv.w;
#pragma unroll
    for (int ct = 0; ct < 4; ++ct) {
      const h4 wa =
          *(const h4*)&sh.p.Wcs[(ct * 16 + lr) * 132 + ks * 16 + lg * 4];
      acc[ct] = __builtin_amdgcn_mfma_f32_16x16x16f16(wa, xb, acc[ct], 0, 0, 0);
    }
  }
  // a[r] = exp(x.avec): row r held by lanes {lr, lr+16, lr+32, lr+48}
  pdot += __shfl_xor(pdot, 16);
  pdot += __shfl_xor(pdot, 32);
  if (lg == 0 && valid) a[r] = __expf(pdot);

  if (valid) {
    struct __align__(8) H4 { __half2 a, b; };
#pragma unroll
    for (int ct = 0; ct < 4; ++ct) {
      H4 st;
      st.a = __floats2half2_rn(acc[ct][0], acc[ct][1]);
      st.b = __floats2half2_rn(acc[ct][2], acc[ct][3]);
      *(H4*)&yh[(size_t)r * 32 + ct * 8 + lg * 2] = st;
    }
  }
}

// ---------------------------------------------------------------------------
// D2: build bucket CSR in LDS + Z (R11's build role verbatim, now alone —
// no proj imbalance/tail). 196 blocks x 1024. Zp consumed by D3 across the
// dispatch boundary.
// ---------------------------------------------------------------------------
__global__ __launch_bounds__(1024) void build_z(
    const unsigned* __restrict__ part, const unsigned* __restrict__ cntm,
    const float* __restrict__ a, float* __restrict__ Zp,
    unsigned short* __restrict__ nbr_g, int* __restrict__ rp_g) {
  __shared__ unsigned eb[EMAX];
  __shared__ unsigned short nbr_s[EMAXP];
  __shared__ int scnt[GRID_P], soff[GRID_P];
  __shared__ int hist[BROWS], rp[BROWS + 1], cur2[BROWS];
  __shared__ int wsum[4];
  __shared__ float red[16];
  const int k = blockIdx.x;
  const int tid = threadIdx.x;
  const int lane = tid & 63;
  const int wv = tid >> 6;

  if (tid < 800)
    ((uint4*)nbr_s)[tid] = make_uint4(SENTPAIR, SENTPAIR, SENTPAIR, SENTPAIR);
  int myc = 0;
  if (tid < GRID_P) {
    myc = (int)cntm[(size_t)k * GRID_P + tid];
    scnt[tid] = myc;
  }
  if (tid < BROWS) hist[tid] = 0;
  int incl = 0;
  if (tid < GRID_P) {
    incl = myc;
#pragma unroll
    for (int off = 1; off < 64; off <<= 1) {
      const int n = __shfl_up(incl, off);
      if (lane >= off) incl += n;
    }
    if (lane == 63) wsum[wv] = incl;
  }
  __syncthreads();  // b1
  if (tid < GRID_P) {
    int woff = 0;
    for (int i = 0; i < wv; ++i) woff += wsum[i];
    soff[tid] = woff + incl - myc;
  }
  int total = wsum[0] + wsum[1] + wsum[2] + wsum[3];
  if (total > EMAX) total = EMAX;
  __syncthreads();  // b2
#pragma unroll 4
  for (int b2 = wv; b2 < GRID_P; b2 += 16) {
    const int c = scnt[b2];
    const int dst = soff[b2] + lane;
    if (lane < c && dst < EMAX)
      eb[dst] = part[((size_t)k * GRID_P + b2) * SLICE_CAP + lane];
  }
  __syncthreads();  // b3
  // hist + per-bucket Z partial in one pass over staged edges
  float z = 0.f;
  const int rbase = k * BROWS;
  for (int i = tid; i < total; i += 1024) {
    const unsigned u = eb[i];
    atomicAdd(&hist[u >> 16], 1);
    z = fmaf(a[rbase + (int)(u >> 16)], a[u & 0xFFFFu], z);
  }
#pragma unroll
  for (int off = 32; off >= 1; off >>= 1) z += __shfl_xor(z, off);
  if ((tid & 63) == 0) red[tid >> 6] = z;
  __syncthreads();  // b4
  if (tid == 0) {
    float t = 0.f;
#pragma unroll
    for (int i = 0; i < 16; ++i) t += red[i];
    atomicAdd(Zp, t);  // consumed by D3 (next dispatch)
  }
  int hincl = 0, pv = 0;
  if (tid < BROWS) {
    const int hv = hist[tid];
    pv = (hv + 7) & ~7;
    hincl = pv;
#pragma unroll
    for (int off = 1; off < 64; off <<= 1) {
      const int n = __shfl_up(hincl, off);
      if (lane >= off) hincl += n;
    }
    if (lane == 63) wsum[wv] = hincl;
  }
  __syncthreads();  // b5
  if (tid < BROWS) {
    int woff = 0;
    for (int i = 0; i < wv; ++i) woff += wsum[i];
    const int excl = woff + hincl - pv;
    rp[tid] = excl;
    cur2[tid] = excl;
    if (tid == BROWS - 1) rp[BROWS] = excl + pv;
  }
  __syncthreads();  // b6
  for (int i = tid; i < total; i += 1024) {
    const unsigned u = eb[i];
    const int pos = atomicAdd(&cur2[u >> 16], 1);
    nbr_s[pos] = (unsigned short)(u & 0xFFFFu);
  }
  __syncthreads();  // b7
  const int ptot = rp[BROWS];
  uint4* dst = (uint4*)&nbr_g[(size_t)k * EMAXP];
  const uint4* srcv = (const uint4*)nbr_s;
  for (int i = tid; i < (ptot >> 3); i += 1024) dst[i] = srcv[i];
  for (int i = tid; i <= BROWS; i += 1024) rp_g[k * (BROWS + 1) + i] = rp[i];
}

// ---------------------------------------------------------------------------
// D3: gather (proven kernel, unchanged). 3136 blocks x 256 thr, ~8
// blocks/CU -> the TLP the latency-bound random yh reads need.
// ---------------------------------------------------------------------------
__global__ __launch_bounds__(256) void gather(
    const unsigned short* __restrict__ nbr_g, const int* __restrict__ rp_g,
    const __half2* __restrict__ yh, const float* __restrict__ a,
    const float* __restrict__ Zp, const float* __restrict__ bias,
    float* __restrict__ out) {
  const int k = blockIdx.x >> 4;    // bucket
  const int seg = blockIdx.x & 15;  // 16-row segment within bucket
  const int tid = threadIdx.x;
  const int g = tid >> 5;           // row group 0..7
  const int cp = tid & 31;          // half2 channel
  const float invZ = 1.f / Zp[0];
  const unsigned short* nb = &nbr_g[(size_t)k * EMAXP];
  const int* rpk = &rp_g[k * (BROWS + 1)];
#pragma unroll
  for (int ri = 0; ri < 2; ++ri) {
    const int rlo = seg * 16 + g * 2 + ri;
    const int r = k * BROWS + rlo;
    if (r >= N_NODES) continue;
    const int beg = rpk[rlo];
    const int d = rpk[rlo + 1] - beg;  // multiple of 8
    float2 acc = make_float2(0.f, 0.f);
    for (int i = 0; i < d; i += 8) {
      const uint4 nv = *(const uint4*)&nb[beg + i];  // uniform -> bcast
      int c[8];
      c[0] = nv.x & 0xFFFF; c[1] = nv.x >> 16;
      c[2] = nv.y & 0xFFFF; c[3] = nv.y >> 16;
      c[4] = nv.z & 0xFFFF; c[5] = nv.z >> 16;
      c[6] = nv.w & 0xFFFF; c[7] = nv.w >> 16;
      float av[8];
      float2 v[8];
#pragma unroll
      for (int j = 0; j < 8; ++j) av[j] = a[c[j]];
#pragma unroll
      for (int j = 0; j < 8; ++j)
        v[j] = __half22float2(yh[(size_t)c[j] * 32 + cp]);
#pragma unroll
      for (int j = 0; j < 8; ++j) {
        acc.x = fmaf(av[j], v[j].x, acc.x);
        acc.y = fmaf(av[j], v[j].y, acc.y);
      }
    }
    const float scale = a[r] * invZ;
    float2 o;
    o.x = tanhf(fmaf(acc.x, scale, bias[cp * 2]));
    o.y = tanhf(fmaf(acc.y, scale, bias[cp * 2 + 1]));
    *(float2*)&out[(size_t)r * 64 + cp * 2] = o;
  }
}

// ---------------------------------------------------------------------------
extern "C" void kernel_launch(void* const* d_in, const int* in_sizes, int n_in,
                              void* d_out, int out_size, void* d_ws,
                              size_t ws_size, hipStream_t stream) {
  const float* x   = (const float*)d_in[0];
  const int*   ei  = (const int*)d_in[1];  // [2, E] int32
  const float* Wl  = (const float*)d_in[2];
  const float* att = (const float*)d_in[3];
  const float* Wo  = (const float*)d_in[4];
  const float* b   = (const float*)d_in[5];
  float* out = (float*)d_out;

  float* ws = (float*)d_ws;
  float*          a     = ws;                           // 50,176 (SENT at 50,000)
  __half2*        yh    = (__half2*)(ws + 50176);       // 50,001 rows x 32 half2
  float*          Zp    = ws + 1650208;                 // 1
  unsigned*       part  = (unsigned*)(ws + 1658532);    // 196*256*48
  unsigned*       cntm  = (unsigned*)(ws + 4066980);    // 50,176
  unsigned short* nbr_g = (unsigned short*)(ws + 4117156); // 196*6400 u16
  int*            rp_g  = (int*)(ws + 4744356);         // 196*257
  // total ~4.79M floats = 19.2 MB

  part_proj<<<GRID_P + 196, 1024, 0, stream>>>(ei, x, Wl, att, Wo, Zp, a, yh,
                                               part, cntm);
  build_z<<<NBUCK, 1024, 0, stream>>>(part, cntm, a, Zp, nbr_g, rp_g);
  gather<<<NBUCK * 16, 256, 0, stream>>>(nbr_g, rp_g, yh, a, Zp, b, out);
}

// Round 13
// 82.299 us; speedup vs baseline: 1.3024x; 1.3024x over previous
//
#include <hip/hip_runtime.h>
#include <hip/hip_fp16.h>
#include <math.h>

#define N_NODES 50000
#define N_EDGES 800000
#define NBUCK 196             // ceil(N/256) coarse buckets (rows r>>8)
#define BROWS 256             // rows per bucket
#define GRID_P 256            // partition blocks in D1
#define SLICE_CAP 48          // per (bucket,block) slice cap; Poisson(16)
#define EMAX 5120             // per-bucket staged edges (unpadded)
#define EMAXP 6400            // per-bucket padded capacity
#define SENT 50000            // sentinel col: a[SENT]=0, yh row zeroed
#define SENTPAIR 0xC350C350u  // (SENT<<16)|SENT

typedef _Float16 h4 __attribute__((ext_vector_type(4)));
typedef float f32x4 __attribute__((ext_vector_type(4)));

// ---------------------------------------------------------------------------
// D1: partition ∥ proj, one dispatch, no intra-dispatch dependencies.
// Blocks 0..255: bucket-partition edges (R11 LDS-staged slices). Blocks
// 256..451: proj — per-block avec + Wc, then 4 MFMA tiles (x direct
// global->fragment), writing yh and a[r]=exp(x.avec).
// R13 fix of R12's 78us: Wc compute now 8-way ILP — thread t owns 8
// consecutive j for one i (1 broadcast Wl + 2 float4 Wo loads feed 8
// independent fmaf chains; 384 loads/thread vs 2048 serial before). Each
// element's m-chain stays in order -> bit-identical Wc.
// ---------------------------------------------------------------------------
union ShD1 {
  struct {
    int cur[NBUCK];
    unsigned sl[NBUCK * SLICE_CAP];  // 37.6KB block-private slices
  } q;
  struct {
    __half Wcs[64 * 132];  // [col][k], stride 132 halves
    float avs[128];
  } p;
};

__global__ __launch_bounds__(1024, 8) void part_proj(
    const int* __restrict__ ei, const float* __restrict__ x,
    const float* __restrict__ Wl, const float* __restrict__ att,
    const float* __restrict__ Wo, float* __restrict__ Zp,
    float* __restrict__ a, __half2* __restrict__ yh,
    unsigned* __restrict__ part, unsigned* __restrict__ cntm) {
  __shared__ ShD1 sh;
  const int bid = blockIdx.x;
  const int tid = threadIdx.x;

  if (bid < GRID_P) {
    // ================= partition role (R11, unchanged) =================
    for (int i = tid; i < NBUCK; i += 1024) sh.q.cur[i] = 0;
    __syncthreads();
    const int G = GRID_P * 1024;
    for (int e = bid * 1024 + tid; e < N_EDGES; e += 2 * G) {
      const int e1 = e + G;
      const bool v1 = e1 < N_EDGES;
      const int r0 = ei[e];
      const int c0 = ei[N_EDGES + e];
      int r1 = 0, c1 = 0;
      if (v1) {
        r1 = ei[e1];
        c1 = ei[N_EDGES + e1];
      }
      const int b0 = r0 >> 8;
      const int p0 = atomicAdd(&sh.q.cur[b0], 1);
      if (p0 < SLICE_CAP)
        sh.q.sl[b0 * SLICE_CAP + p0] =
            ((unsigned)(r0 & 255) << 16) | (unsigned)c0;
      if (v1) {
        const int b1 = r1 >> 8;
        const int p1 = atomicAdd(&sh.q.cur[b1], 1);
        if (p1 < SLICE_CAP)
          sh.q.sl[b1 * SLICE_CAP + p1] =
              ((unsigned)(r1 & 255) << 16) | (unsigned)c1;
      }
    }
    __syncthreads();
    const int lane = tid & 63;
    const int wv = tid >> 6;
    for (int b2 = wv; b2 < NBUCK; b2 += 16) {
      const int n = min(sh.q.cur[b2], SLICE_CAP);
      if (lane < n)
        part[((size_t)b2 * GRID_P + bid) * SLICE_CAP + lane] =
            sh.q.sl[b2 * SLICE_CAP + lane];
    }
    for (int i = tid; i < NBUCK; i += 1024)
      cntm[i * GRID_P + bid] = (unsigned)min(sh.q.cur[i], SLICE_CAP);
    return;
  }

  // ================= proj role: self-contained (own avec + Wc) ==========
  const int pb = bid - GRID_P;  // 0..195
  // avec = 0.5 * Wl @ att (same chain as before -> identical bits)
  if (tid < 128) {
    float acc = 0.f;
    for (int m = 0; m < 128; ++m)
      acc = fmaf(Wl[tid * 128 + m], att[m], acc);
    sh.p.avs[tid] = 0.5f * acc;
  }
  // Wc = Wl @ Wo: thread t -> i = t>>3, j = j0..j0+7 (j0=(t&7)*8).
  // 8 independent fmaf chains, each in m-order -> bit-identical elements.
  {
    const int i = tid >> 3;
    const int j0 = (tid & 7) * 8;
    float acc8[8];
#pragma unroll
    for (int q = 0; q < 8; ++q) acc8[q] = 0.f;
    const float* wlrow = Wl + i * 128;
#pragma unroll 4
    for (int m = 0; m < 128; ++m) {
      const float wl = wlrow[m];
      const float4 wo0 = *(const float4*)&Wo[m * 64 + j0];
      const float4 wo1 = *(const float4*)&Wo[m * 64 + j0 + 4];
      acc8[0] = fmaf(wl, wo0.x, acc8[0]);
      acc8[1] = fmaf(wl, wo0.y, acc8[1]);
      acc8[2] = fmaf(wl, wo0.z, acc8[2]);
      acc8[3] = fmaf(wl, wo0.w, acc8[3]);
      acc8[4] = fmaf(wl, wo1.x, acc8[4]);
      acc8[5] = fmaf(wl, wo1.y, acc8[5]);
      acc8[6] = fmaf(wl, wo1.z, acc8[6]);
      acc8[7] = fmaf(wl, wo1.w, acc8[7]);
    }
#pragma unroll
    for (int q = 0; q < 8; ++q)
      sh.p.Wcs[(j0 + q) * 132 + i] = __float2half(acc8[q]);
  }
  if (pb == 0) {  // sentinels + Zp=0 (consumed from D2 onward)
    if (tid == 1023) a[SENT] = 0.f;
    if (tid == 959) Zp[0] = 0.f;
    if (tid >= 960 && tid < 992)
      yh[(size_t)SENT * 32 + (tid - 960)] = __floats2half2_rn(0.f, 0.f);
  }
  __syncthreads();

  const int g4 = tid >> 8;       // tile-in-block 0..3
  const int t = pb * 4 + g4;     // global tile id (<= 783)
  const int row0 = t * 64;
  if (row0 >= N_NODES) return;   // after the only barrier: safe
  const int w = (tid >> 6) & 3;  // wave-in-tile
  const int l = tid & 63;
  const int lr = l & 15;
  const int lg = l >> 4;
  const int r = row0 + w * 16 + lr;  // this lane's x row
  const bool valid = r < N_NODES;
  const float* xrow = x + (size_t)(valid ? r : 0) * 128;

  f32x4 acc[4];
#pragma unroll
  for (int ct = 0; ct < 4; ++ct) acc[ct] = (f32x4){0.f, 0.f, 0.f, 0.f};
  float pdot = 0.f;

#pragma unroll
  for (int ks = 0; ks < 8; ++ks) {
    float4 xv = *(const float4*)(xrow + ks * 16 + lg * 4);
    if (!valid) xv = make_float4(0.f, 0.f, 0.f, 0.f);
    pdot += xv.x * sh.p.avs[ks * 16 + lg * 4] +
            xv.y * sh.p.avs[ks * 16 + lg * 4 + 1] +
            xv.z * sh.p.avs[ks * 16 + lg * 4 + 2] +
            xv.w * sh.p.avs[ks * 16 + lg * 4 + 3];
    h4 xb;
    xb[0] = (_Float16)xv.x;
    xb[1] = (_Float16)xv.y;
    xb[2] = (_Float16)xv.z;
    xb[3] = (_Float16)xv.w;
#pragma unroll
    for (int ct = 0; ct < 4; ++ct) {
      const h4 wa =
          *(const h4*)&sh.p.Wcs[(ct * 16 + lr) * 132 + ks * 16 + lg * 4];
      acc[ct] = __builtin_amdgcn_mfma_f32_16x16x16f16(wa, xb, acc[ct], 0, 0, 0);
    }
  }
  // a[r] = exp(x.avec): row r held by lanes {lr, lr+16, lr+32, lr+48}
  pdot += __shfl_xor(pdot, 16);
  pdot += __shfl_xor(pdot, 32);
  if (lg == 0 && valid) a[r] = __expf(pdot);

  if (valid) {
    struct __align__(8) H4 { __half2 a, b; };
#pragma unroll
    for (int ct = 0; ct < 4; ++ct) {
      H4 st;
      st.a = __floats2half2_rn(acc[ct][0], acc[ct][1]);
      st.b = __floats2half2_rn(acc[ct][2], acc[ct][3]);
      *(H4*)&yh[(size_t)r * 32 + ct * 8 + lg * 2] = st;
    }
  }
}

// ---------------------------------------------------------------------------
// D2: build bucket CSR in LDS + Z (R11's build role verbatim). 196 blocks
// x 1024. Zp consumed by D3 across the dispatch boundary.
// ---------------------------------------------------------------------------
__global__ __launch_bounds__(1024) void build_z(
    const unsigned* __restrict__ part, const unsigned* __restrict__ cntm,
    const float* __restrict__ a, float* __restrict__ Zp,
    unsigned short* __restrict__ nbr_g, int* __restrict__ rp_g) {
  __shared__ unsigned eb[EMAX];
  __shared__ unsigned short nbr_s[EMAXP];
  __shared__ int scnt[GRID_P], soff[GRID_P];
  __shared__ int hist[BROWS], rp[BROWS + 1], cur2[BROWS];
  __shared__ int wsum[4];
  __shared__ float red[16];
  const int k = blockIdx.x;
  const int tid = threadIdx.x;
  const int lane = tid & 63;
  const int wv = tid >> 6;

  if (tid < 800)
    ((uint4*)nbr_s)[tid] = make_uint4(SENTPAIR, SENTPAIR, SENTPAIR, SENTPAIR);
  int myc = 0;
  if (tid < GRID_P) {
    myc = (int)cntm[(size_t)k * GRID_P + tid];
    scnt[tid] = myc;
  }
  if (tid < BROWS) hist[tid] = 0;
  int incl = 0;
  if (tid < GRID_P) {
    incl = myc;
#pragma unroll
    for (int off = 1; off < 64; off <<= 1) {
      const int n = __shfl_up(incl, off);
      if (lane >= off) incl += n;
    }
    if (lane == 63) wsum[wv] = incl;
  }
  __syncthreads();  // b1
  if (tid < GRID_P) {
    int woff = 0;
    for (int i = 0; i < wv; ++i) woff += wsum[i];
    soff[tid] = woff + incl - myc;
  }
  int total = wsum[0] + wsum[1] + wsum[2] + wsum[3];
  if (total > EMAX) total = EMAX;
  __syncthreads();  // b2
#pragma unroll 4
  for (int b2 = wv; b2 < GRID_P; b2 += 16) {
    const int c = scnt[b2];
    const int dst = soff[b2] + lane;
    if (lane < c && dst < EMAX)
      eb[dst] = part[((size_t)k * GRID_P + b2) * SLICE_CAP + lane];
  }
  __syncthreads();  // b3
  // hist + per-bucket Z partial in one pass over staged edges
  float z = 0.f;
  const int rbase = k * BROWS;
  for (int i = tid; i < total; i += 1024) {
    const unsigned u = eb[i];
    atomicAdd(&hist[u >> 16], 1);
    z = fmaf(a[rbase + (int)(u >> 16)], a[u & 0xFFFFu], z);
  }
#pragma unroll
  for (int off = 32; off >= 1; off >>= 1) z += __shfl_xor(z, off);
  if ((tid & 63) == 0) red[tid >> 6] = z;
  __syncthreads();  // b4
  if (tid == 0) {
    float t = 0.f;
#pragma unroll
    for (int i = 0; i < 16; ++i) t += red[i];
    atomicAdd(Zp, t);  // consumed by D3 (next dispatch)
  }
  int hincl = 0, pv = 0;
  if (tid < BROWS) {
    const int hv = hist[tid];
    pv = (hv + 7) & ~7;
    hincl = pv;
#pragma unroll
    for (int off = 1; off < 64; off <<= 1) {
      const int n = __shfl_up(hincl, off);
      if (lane >= off) hincl += n;
    }
    if (lane == 63) wsum[wv] = hincl;
  }
  __syncthreads();  // b5
  if (tid < BROWS) {
    int woff = 0;
    for (int i = 0; i < wv; ++i) woff += wsum[i];
    const int excl = woff + hincl - pv;
    rp[tid] = excl;
    cur2[tid] = excl;
    if (tid == BROWS - 1) rp[BROWS] = excl + pv;
  }
  __syncthreads();  // b6
  for (int i = tid; i < total; i += 1024) {
    const unsigned u = eb[i];
    const int pos = atomicAdd(&cur2[u >> 16], 1);
    nbr_s[pos] = (unsigned short)(u & 0xFFFFu);
  }
  __syncthreads();  // b7
  const int ptot = rp[BROWS];
  uint4* dst = (uint4*)&nbr_g[(size_t)k * EMAXP];
  const uint4* srcv = (const uint4*)nbr_s;
  for (int i = tid; i < (ptot >> 3); i += 1024) dst[i] = srcv[i];
  for (int i = tid; i <= BROWS; i += 1024) rp_g[k * (BROWS + 1) + i] = rp[i];
}

// ---------------------------------------------------------------------------
// D3: gather (proven kernel, unchanged). 3136 blocks x 256 thr, ~8
// blocks/CU -> the TLP the latency-bound random yh reads need.
// ---------------------------------------------------------------------------
__global__ __launch_bounds__(256) void gather(
    const unsigned short* __restrict__ nbr_g, const int* __restrict__ rp_g,
    const __half2* __restrict__ yh, const float* __restrict__ a,
    const float* __restrict__ Zp, const float* __restrict__ bias,
    float* __restrict__ out) {
  const int k = blockIdx.x >> 4;    // bucket
  const int seg = blockIdx.x & 15;  // 16-row segment within bucket
  const int tid = threadIdx.x;
  const int g = tid >> 5;           // row group 0..7
  const int cp = tid & 31;          // half2 channel
  const float invZ = 1.f / Zp[0];
  const unsigned short* nb = &nbr_g[(size_t)k * EMAXP];
  const int* rpk = &rp_g[k * (BROWS + 1)];
#pragma unroll
  for (int ri = 0; ri < 2; ++ri) {
    const int rlo = seg * 16 + g * 2 + ri;
    const int r = k * BROWS + rlo;
    if (r >= N_NODES) continue;
    const int beg = rpk[rlo];
    const int d = rpk[rlo + 1] - beg;  // multiple of 8
    float2 acc = make_float2(0.f, 0.f);
    for (int i = 0; i < d; i += 8) {
      const uint4 nv = *(const uint4*)&nb[beg + i];  // uniform -> bcast
      int c[8];
      c[0] = nv.x & 0xFFFF; c[1] = nv.x >> 16;
      c[2] = nv.y & 0xFFFF; c[3] = nv.y >> 16;
      c[4] = nv.z & 0xFFFF; c[5] = nv.z >> 16;
      c[6] = nv.w & 0xFFFF; c[7] = nv.w >> 16;
      float av[8];
      float2 v[8];
#pragma unroll
      for (int j = 0; j < 8; ++j) av[j] = a[c[j]];
#pragma unroll
      for (int j = 0; j < 8; ++j)
        v[j] = __half22float2(yh[(size_t)c[j] * 32 + cp]);
#pragma unroll
      for (int j = 0; j < 8; ++j) {
        acc.x = fmaf(av[j], v[j].x, acc.x);
        acc.y = fmaf(av[j], v[j].y, acc.y);
      }
    }
    const float scale = a[r] * invZ;
    float2 o;
    o.x = tanhf(fmaf(acc.x, scale, bias[cp * 2]));
    o.y = tanhf(fmaf(acc.y, scale, bias[cp * 2 + 1]));
    *(float2*)&out[(size_t)r * 64 + cp * 2] = o;
  }
}

// ---------------------------------------------------------------------------
extern "C" void kernel_launch(void* const* d_in, const int* in_sizes, int n_in,
                              void* d_out, int out_size, void* d_ws,
                              size_t ws_size, hipStream_t stream) {
  const float* x   = (const float*)d_in[0];
  const int*   ei  = (const int*)d_in[1];  // [2, E] int32
  const float* Wl  = (const float*)d_in[2];
  const float* att = (const float*)d_in[3];
  const float* Wo  = (const float*)d_in[4];
  const float* b   = (const float*)d_in[5];
  float* out = (float*)d_out;

  float* ws = (float*)d_ws;
  float*          a     = ws;                           // 50,176 (SENT at 50,000)
  __half2*        yh    = (__half2*)(ws + 50176);       // 50,001 rows x 32 half2
  float*          Zp    = ws + 1650208;                 // 1
  unsigned*       part  = (unsigned*)(ws + 1658532);    // 196*256*48
  unsigned*       cntm  = (unsigned*)(ws + 4066980);    // 50,176
  unsigned short* nbr_g = (unsigned short*)(ws + 4117156); // 196*6400 u16
  int*            rp_g  = (int*)(ws + 4744356);         // 196*257
  // total ~4.79M floats = 19.2 MB

  part_proj<<<GRID_P + 196, 1024, 0, stream>>>(ei, x, Wl, att, Wo, Zp, a, yh,
                                               part, cntm);
  build_z<<<NBUCK, 1024, 0, stream>>>(part, cntm, a, Zp, nbr_g, rp_g);
  gather<<<NBUCK * 16, 256, 0, stream>>>(nbr_g, rp_g, yh, a, Zp, b, out);
}

// Round 14
// 51.871 us; speedup vs baseline: 2.0663x; 1.5866x over previous
//
#include <hip/hip_runtime.h>
#include <hip/hip_fp16.h>
#include <math.h>

#define N_NODES 50000
#define N_EDGES 800000
#define NBUCK 196             // ceil(N/256) coarse buckets (rows r>>8)
#define BROWS 256             // rows per bucket
#define GRID_P 256            // partition blocks in K1
#define SLICE_CAP 48          // per (bucket,block) slice cap; Poisson(16)
#define EMAX 5120             // per-bucket staged edges (unpadded)
#define EMAXP 6400            // per-bucket padded capacity
#define SENT 50000            // sentinel col: a[SENT]=0, yh row zeroed
#define SENTPAIR 0xC350C350u  // (SENT<<16)|SENT

typedef _Float16 h4 __attribute__((ext_vector_type(4)));
typedef float f32x4 __attribute__((ext_vector_type(4)));

// ---------------------------------------------------------------------------
// K1: partition ∥ Wc-prep ∥ a-fill, one dispatch (R11 verbatim — measured
// 52.0us total). Partition stages its slices in LDS and flushes coalesced
// (kills ~6x write amplification). a-fill computes its own avec (cheap,
// wide) so no intra-dispatch dependency exists anywhere.
// ---------------------------------------------------------------------------
__global__ __launch_bounds__(1024) void part_prep_a(
    const int* __restrict__ ei, const float* __restrict__ x,
    const float* __restrict__ Wl, const float* __restrict__ att,
    const float* __restrict__ Wo, float* __restrict__ Wc,
    float* __restrict__ Zp, float* __restrict__ a,
    unsigned* __restrict__ part, unsigned* __restrict__ cntm) {
  const int bid = blockIdx.x;
  const int tid = threadIdx.x;
  if (bid >= GRID_P + 8) {
    // ================= a-fill role (196 blocks x 256 rows) =================
    __shared__ float avs[128];
    const int ab = bid - (GRID_P + 8);  // 0..195
    if (tid < 128) {
      float acc = 0.f;
      for (int m = 0; m < 128; ++m)
        acc = fmaf(Wl[tid * 128 + m], att[m], acc);  // same chain as before
      avs[tid] = 0.5f * acc;
    }
    if (ab == 0 && tid == 1023) a[SENT] = 0.f;
    __syncthreads();
    const int r0 = ab * 256;
    for (int m = 0; m < 8; ++m) {
      const int i = m * 1024 + tid;     // 8192 = 256 rows x 32 float4-cols
      const int row = i >> 5, c4 = i & 31;
      const int r = r0 + row;
      float4 v = make_float4(0.f, 0.f, 0.f, 0.f);
      if (r < N_NODES) v = ((const float4*)x)[(size_t)r * 32 + c4];
      float p = v.x * avs[c4 * 4] + v.y * avs[c4 * 4 + 1] +
                v.z * avs[c4 * 4 + 2] + v.w * avs[c4 * 4 + 3];
#pragma unroll
      for (int off = 1; off < 32; off <<= 1) p += __shfl_xor(p, off);
      if ((tid & 31) == 0 && r < N_NODES) a[r] = __expf(p);
    }
    return;
  }
  if (bid >= GRID_P) {
    // ================= Wc role (8 blocks) =================
    const int pb = bid - GRID_P;
    const int idx = pb * 1024 + tid;
    const int i = idx >> 6, j = idx & 63;
    float acc = 0.f;
    for (int m = 0; m < 128; ++m)
      acc = fmaf(Wl[i * 128 + m], Wo[m * 64 + j], acc);
    Wc[idx] = acc;
    if (pb == 0 && tid == 0) Zp[0] = 0.f;
    return;
  }
  // ================= partition role (LDS-staged slices) =================
  __shared__ int cur[NBUCK];
  __shared__ unsigned sl[NBUCK * SLICE_CAP];  // 37.6KB: block-private slices
  for (int i = tid; i < NBUCK; i += 1024) cur[i] = 0;
  __syncthreads();
  const int G = GRID_P * 1024;
  for (int e = bid * 1024 + tid; e < N_EDGES; e += 2 * G) {
    const int e1 = e + G;
    const bool v1 = e1 < N_EDGES;
    const int r0 = ei[e];
    const int c0 = ei[N_EDGES + e];
    int r1 = 0, c1 = 0;
    if (v1) {
      r1 = ei[e1];
      c1 = ei[N_EDGES + e1];
    }
    const int b0 = r0 >> 8;
    const int p0 = atomicAdd(&cur[b0], 1);
    if (p0 < SLICE_CAP)
      sl[b0 * SLICE_CAP + p0] = ((unsigned)(r0 & 255) << 16) | (unsigned)c0;
    if (v1) {
      const int b1 = r1 >> 8;
      const int p1 = atomicAdd(&cur[b1], 1);
      if (p1 < SLICE_CAP)
        sl[b1 * SLICE_CAP + p1] = ((unsigned)(r1 & 255) << 16) | (unsigned)c1;
    }
  }
  __syncthreads();
  // coalesced flush: wave wv handles slices {wv, wv+16, ...}; lanes write
  // the occupied prefix contiguously (4B/lane bursts -> full coalescing).
  const int lane = tid & 63;
  const int wv = tid >> 6;
  for (int b2 = wv; b2 < NBUCK; b2 += 16) {
    const int n = min(cur[b2], SLICE_CAP);
    if (lane < n)
      part[((size_t)b2 * GRID_P + bid) * SLICE_CAP + lane] =
          sl[b2 * SLICE_CAP + lane];
  }
  for (int i = tid; i < NBUCK; i += 1024)
    cntm[i * GRID_P + bid] = (unsigned)min(cur[i], SLICE_CAP);
}

// ---------------------------------------------------------------------------
// K2: proj ∥ build+Z in ONE dispatch (R11 verbatim). Blocks 0..195: build
// bucket CSR in LDS + Z. Blocks 196..391: proj, 4 MFMA tiles/block, x read
// direct global->fragment. 392 blocks x 1024, 2 blocks/CU -> one round,
// wall = max(build, proj) not sum.
// ---------------------------------------------------------------------------
union ShU {
  struct {
    unsigned eb[EMAX];
    unsigned short nbr_s[EMAXP];
    int scnt[GRID_P], soff[GRID_P];
    int hist[BROWS], rp[BROWS + 1], cur2[BROWS];
    int wsum[4];
    float red[16];
  } b;
  struct {
    __half Wcs[64 * 132];
  } p;
};

__global__ __launch_bounds__(1024, 8) void proj_build(
    const float* __restrict__ x, const float* __restrict__ Wc,
    const unsigned* __restrict__ part, const unsigned* __restrict__ cntm,
    const float* __restrict__ a, float* __restrict__ Zp,
    __half2* __restrict__ yh, unsigned short* __restrict__ nbr_g,
    int* __restrict__ rp_g) {
  __shared__ ShU sh;
  const int bid = blockIdx.x;
  const int tid = threadIdx.x;

  if (bid < NBUCK) {
    // ================= build role (incl. Z) =================
    const int k = bid;
    const int lane = tid & 63;
    const int wv = tid >> 6;
    if (tid < 800)
      ((uint4*)sh.b.nbr_s)[tid] =
          make_uint4(SENTPAIR, SENTPAIR, SENTPAIR, SENTPAIR);
    int myc = 0;
    if (tid < GRID_P) {
      myc = (int)cntm[(size_t)k * GRID_P + tid];
      sh.b.scnt[tid] = myc;
    }
    if (tid < BROWS) sh.b.hist[tid] = 0;
    int incl = 0;
    if (tid < GRID_P) {
      incl = myc;
#pragma unroll
      for (int off = 1; off < 64; off <<= 1) {
        const int n = __shfl_up(incl, off);
        if (lane >= off) incl += n;
      }
      if (lane == 63) sh.b.wsum[wv] = incl;
    }
    __syncthreads();  // b1
    if (tid < GRID_P) {
      int woff = 0;
      for (int i = 0; i < wv; ++i) woff += sh.b.wsum[i];
      sh.b.soff[tid] = woff + incl - myc;
    }
    int total = sh.b.wsum[0] + sh.b.wsum[1] + sh.b.wsum[2] + sh.b.wsum[3];
    if (total > EMAX) total = EMAX;
    __syncthreads();  // b2
#pragma unroll 4
    for (int b2 = wv; b2 < GRID_P; b2 += 16) {
      const int c = sh.b.scnt[b2];
      const int dst = sh.b.soff[b2] + lane;
      if (lane < c && dst < EMAX)
        sh.b.eb[dst] = part[((size_t)k * GRID_P + b2) * SLICE_CAP + lane];
    }
    __syncthreads();  // b3
    // hist + per-bucket Z partial in one pass over staged edges
    float z = 0.f;
    const int rbase = k * BROWS;
    for (int i = tid; i < total; i += 1024) {
      const unsigned u = sh.b.eb[i];
      atomicAdd(&sh.b.hist[u >> 16], 1);
      z = fmaf(a[rbase + (int)(u >> 16)], a[u & 0xFFFFu], z);
    }
#pragma unroll
    for (int off = 32; off >= 1; off >>= 1) z += __shfl_xor(z, off);
    if ((tid & 63) == 0) sh.b.red[tid >> 6] = z;
    __syncthreads();  // b4
    if (tid == 0) {
      float t = 0.f;
#pragma unroll
      for (int i = 0; i < 16; ++i) t += sh.b.red[i];
      atomicAdd(Zp, t);  // consumed by K3 (next dispatch)
    }
    int hincl = 0, pv = 0;
    if (tid < BROWS) {
      const int hv = sh.b.hist[tid];
      pv = (hv + 7) & ~7;
      hincl = pv;
#pragma unroll
      for (int off = 1; off < 64; off <<= 1) {
        const int n = __shfl_up(hincl, off);
        if (lane >= off) hincl += n;
      }
      if (lane == 63) sh.b.wsum[wv] = hincl;
    }
    __syncthreads();  // b5
    if (tid < BROWS) {
      int woff = 0;
      for (int i = 0; i < wv; ++i) woff += sh.b.wsum[i];
      const int excl = woff + hincl - pv;
      sh.b.rp[tid] = excl;
      sh.b.cur2[tid] = excl;
      if (tid == BROWS - 1) sh.b.rp[BROWS] = excl + pv;
    }
    __syncthreads();  // b6
    for (int i = tid; i < total; i += 1024) {
      const unsigned u = sh.b.eb[i];
      const int pos = atomicAdd(&sh.b.cur2[u >> 16], 1);
      sh.b.nbr_s[pos] = (unsigned short)(u & 0xFFFFu);
    }
    __syncthreads();  // b7
    const int ptot = sh.b.rp[BROWS];
    uint4* dst = (uint4*)&nbr_g[(size_t)k * EMAXP];
    const uint4* srcv = (const uint4*)sh.b.nbr_s;
    for (int i = tid; i < (ptot >> 3); i += 1024) dst[i] = srcv[i];
    for (int i = tid; i <= BROWS; i += 1024)
      rp_g[k * (BROWS + 1) + i] = sh.b.rp[i];
    return;
  }

  // ================= proj role: 4 tiles per block =================
  const int pb = bid - NBUCK;  // 0..195
  for (int i = tid; i < 2048; i += 1024) {
    const int kk = i >> 4, c4 = i & 15;
    const float4 w = ((const float4*)Wc)[i];
    sh.p.Wcs[(c4 * 4 + 0) * 132 + kk] = __float2half(w.x);
    sh.p.Wcs[(c4 * 4 + 1) * 132 + kk] = __float2half(w.y);
    sh.p.Wcs[(c4 * 4 + 2) * 132 + kk] = __float2half(w.z);
    sh.p.Wcs[(c4 * 4 + 3) * 132 + kk] = __float2half(w.w);
  }
  if (pb == 0 && tid >= 960 && tid < 992)  // sentinel yh row (read in K3)
    yh[(size_t)SENT * 32 + (tid - 960)] = __floats2half2_rn(0.f, 0.f);
  __syncthreads();

  const int g4 = tid >> 8;       // tile-in-block 0..3
  const int t = pb * 4 + g4;     // global tile id
  const int row0 = t * 64;
  if (row0 >= N_NODES) return;   // after the only barrier: safe
  const int w = (tid >> 6) & 3;  // wave-in-tile
  const int l = tid & 63;
  const int lr = l & 15;
  const int lg = l >> 4;
  const int r = row0 + w * 16 + lr;  // this lane's x row
  const bool valid = r < N_NODES;
  const float* xrow = x + (size_t)(valid ? r : 0) * 128;

  f32x4 acc[4];
#pragma unroll
  for (int ct = 0; ct < 4; ++ct) acc[ct] = (f32x4){0.f, 0.f, 0.f, 0.f};

#pragma unroll
  for (int ks = 0; ks < 8; ++ks) {
    float4 xv = *(const float4*)(xrow + ks * 16 + lg * 4);
    if (!valid) xv = make_float4(0.f, 0.f, 0.f, 0.f);
    h4 xb;
    xb[0] = (_Float16)xv.x;
    xb[1] = (_Float16)xv.y;
    xb[2] = (_Float16)xv.z;
    xb[3] = (_Float16)xv.w;
#pragma unroll
    for (int ct = 0; ct < 4; ++ct) {
      const h4 wa =
          *(const h4*)&sh.p.Wcs[(ct * 16 + lr) * 132 + ks * 16 + lg * 4];
      acc[ct] = __builtin_amdgcn_mfma_f32_16x16x16f16(wa, xb, acc[ct], 0, 0, 0);
    }
  }
  if (valid) {
    struct __align__(8) H4 { __half2 a, b; };
#pragma unroll
    for (int ct = 0; ct < 4; ++ct) {
      H4 st;
      st.a = __floats2half2_rn(acc[ct][0], acc[ct][1]);
      st.b = __floats2half2_rn(acc[ct][2], acc[ct][3]);
      *(H4*)&yh[(size_t)r * 32 + ct * 8 + lg * 2] = st;
    }
  }
}

// ---------------------------------------------------------------------------
// K3: gather (proven kernel, unchanged). 3136 blocks x 256 thr, ~8
// blocks/CU -> the TLP the latency-bound random yh reads need. invZ read
// directly from Zp (produced by K2's build role; dispatch boundary = free
// visibility).
// ---------------------------------------------------------------------------
__global__ __launch_bounds__(256) void gather(
    const unsigned short* __restrict__ nbr_g, const int* __restrict__ rp_g,
    const __half2* __restrict__ yh, const float* __restrict__ a,
    const float* __restrict__ Zp, const float* __restrict__ bias,
    float* __restrict__ out) {
  const int k = blockIdx.x >> 4;    // bucket
  const int seg = blockIdx.x & 15;  // 16-row segment within bucket
  const int tid = threadIdx.x;
  const int g = tid >> 5;           // row group 0..7
  const int cp = tid & 31;          // half2 channel
  const float invZ = 1.f / Zp[0];
  const unsigned short* nb = &nbr_g[(size_t)k * EMAXP];
  const int* rpk = &rp_g[k * (BROWS + 1)];
#pragma unroll
  for (int ri = 0; ri < 2; ++ri) {
    const int rlo = seg * 16 + g * 2 + ri;
    const int r = k * BROWS + rlo;
    if (r >= N_NODES) continue;
    const int beg = rpk[rlo];
    const int d = rpk[rlo + 1] - beg;  // multiple of 8
    float2 acc = make_float2(0.f, 0.f);
    for (int i = 0; i < d; i += 8) {
      const uint4 nv = *(const uint4*)&nb[beg + i];  // uniform -> bcast
      int c[8];
      c[0] = nv.x & 0xFFFF; c[1] = nv.x >> 16;
      c[2] = nv.y & 0xFFFF; c[3] = nv.y >> 16;
      c[4] = nv.z & 0xFFFF; c[5] = nv.z >> 16;
      c[6] = nv.w & 0xFFFF; c[7] = nv.w >> 16;
      float av[8];
      float2 v[8];
#pragma unroll
      for (int j = 0; j < 8; ++j) av[j] = a[c[j]];
#pragma unroll
      for (int j = 0; j < 8; ++j)
        v[j] = __half22float2(yh[(size_t)c[j] * 32 + cp]);
#pragma unroll
      for (int j = 0; j < 8; ++j) {
        acc.x = fmaf(av[j], v[j].x, acc.x);
        acc.y = fmaf(av[j], v[j].y, acc.y);
      }
    }
    const float scale = a[r] * invZ;
    float2 o;
    o.x = tanhf(fmaf(acc.x, scale, bias[cp * 2]));
    o.y = tanhf(fmaf(acc.y, scale, bias[cp * 2 + 1]));
    *(float2*)&out[(size_t)r * 64 + cp * 2] = o;
  }
}

// ---------------------------------------------------------------------------
extern "C" void kernel_launch(void* const* d_in, const int* in_sizes, int n_in,
                              void* d_out, int out_size, void* d_ws,
                              size_t ws_size, hipStream_t stream) {
  const float* x   = (const float*)d_in[0];
  const int*   ei  = (const int*)d_in[1];  // [2, E] int32
  const float* Wl  = (const float*)d_in[2];
  const float* att = (const float*)d_in[3];
  const float* Wo  = (const float*)d_in[4];
  const float* b   = (const float*)d_in[5];
  float* out = (float*)d_out;

  float* ws = (float*)d_ws;
  float*          a     = ws;                           // 50,176 (SENT at 50,000)
  __half2*        yh    = (__half2*)(ws + 50176);       // 50,001 rows x 32 half2
  float*          Zp    = ws + 1650208;                 // 1
  float*          Wc    = ws + 1650212;                 // 8,192
  unsigned*       part  = (unsigned*)(ws + 1658532);    // 196*256*48
  unsigned*       cntm  = (unsigned*)(ws + 4066980);    // 50,176
  unsigned short* nbr_g = (unsigned short*)(ws + 4117156); // 196*6400 u16
  int*            rp_g  = (int*)(ws + 4744356);         // 196*257
  // total ~4.79M floats = 19.2 MB

  part_prep_a<<<GRID_P + 8 + 196, 1024, 0, stream>>>(ei, x, Wl, att, Wo, Wc,
                                                     Zp, a, part, cntm);
  proj_build<<<NBUCK + 196, 1024, 0, stream>>>(x, Wc, part, cntm, a, Zp, yh,
                                               nbr_g, rp_g);
  gather<<<NBUCK * 16, 256, 0, stream>>>(nbr_g, rp_g, yh, a, Zp, b, out);
}